// Round 1
// baseline (350.725 us; speedup 1.0000x reference)
//
#include <hip/hip_runtime.h>
#include <hip/hip_bf16.h>
#include <cstdint>

// ---------------------------------------------------------------------------
// TransducerJoint: out[b,t,u,:] = tanh(f[b,t,:] + g[b,u,:]) @ W_joint + b_joint
//   f = enc @ W_enc + b_enc   [B*T, 512]
//   g = pred @ W_pred + b_pred [B*U, 512]
// Strategy: bf16 MFMA GEMMs; materialize A = tanh(f+g) as bf16 in ws (123 MB)
// so the dominant [120000 x 1024 x 512] GEMM is a clean m97-style kernel.
// ---------------------------------------------------------------------------

typedef __attribute__((ext_vector_type(4))) float f32x4;
typedef __attribute__((ext_vector_type(8))) short s16x8;

#define B_ 4
#define T_ 300
#define U_ 100
#define DM 512
#define VOC 1024
#define M_MAIN (B_*T_*U_)       // 120000
#define M_MAIN_PAD 120064       // 938 * 128
#define M_ENC_PAD 1280          // 10 * 128 (valid 1200)
#define M_PRED_PAD 512          // 4 * 128 (valid 400)

__device__ __forceinline__ unsigned short f2bf(float x) {
  unsigned int u = __builtin_bit_cast(unsigned int, x);
  u += 0x7FFFu + ((u >> 16) & 1u);          // round-to-nearest-even
  return (unsigned short)(u >> 16);
}

__device__ __forceinline__ float fast_tanh(float x) {
  // tanh(x) = 1 - 2/(e^{2x}+1);  e^{2x} = 2^{2x*log2(e)}
  float e = __builtin_amdgcn_exp2f(x * 2.8853900817779268f);
  return fmaf(-2.0f, __builtin_amdgcn_rcpf(e + 1.0f), 1.0f);
}

__device__ __forceinline__ void gload_lds16(const void* g, void* l) {
  __builtin_amdgcn_global_load_lds(
      (const __attribute__((address_space(1))) void*)g,
      (__attribute__((address_space(3))) void*)l, 16, 0, 0);
}

// ---------------------------------------------------------------------------
// bf16 convert + row-pad (zeros) for enc and pred, one launch.
// grid: 448 blocks x 256 (enc: 320 blocks, pred: 128), 8 elems/thread.
// ---------------------------------------------------------------------------
__global__ void k_cvtpad(const float* __restrict__ enc, const float* __restrict__ pred,
                         unsigned short* __restrict__ encb, unsigned short* __restrict__ predb)
{
  int idx = blockIdx.x * 256 + threadIdx.x;
  const int encCh = M_ENC_PAD * 64;   // 81920 16B-chunks
  const float* src; unsigned short* dst; int Mv; int id2;
  if (idx < encCh) { src = enc; dst = encb; Mv = B_*T_; id2 = idx; }
  else            { id2 = idx - encCh; src = pred; dst = predb; Mv = B_*U_; }
  int r = id2 >> 6, k = (id2 & 63) * 8;
  s16x8 v;
  if (r < Mv) {
    f32x4 a = *(const f32x4*)(src + r*DM + k);
    f32x4 b = *(const f32x4*)(src + r*DM + k + 4);
#pragma unroll
    for (int j = 0; j < 4; ++j) { v[j] = (short)f2bf(a[j]); v[4+j] = (short)f2bf(b[j]); }
  } else {
#pragma unroll
    for (int j = 0; j < 8; ++j) v[j] = 0;
  }
  *(s16x8*)(dst + (long)id2 * 8) = v;
}

// ---------------------------------------------------------------------------
// Transpose fp32 [R][C] -> bf16 [C][R] via 32x32 LDS tile. z selects matrix.
// ---------------------------------------------------------------------------
__global__ void k_transpose3(const float* __restrict__ We, const float* __restrict__ Wp,
                             const float* __restrict__ Wj,
                             unsigned short* __restrict__ WeT, unsigned short* __restrict__ WpT,
                             unsigned short* __restrict__ WjT)
{
  __shared__ float tile[32][33];
  const float* src; unsigned short* dst; int Ccols;
  const int R = 512;
  if (blockIdx.z == 0)      { src = We; dst = WeT; Ccols = 512; }
  else if (blockIdx.z == 1) { src = Wp; dst = WpT; Ccols = 512; }
  else                      { src = Wj; dst = WjT; Ccols = 1024; }
  int bx = blockIdx.x, by = blockIdx.y;
  if (bx * 32 >= Ccols) return;
  int x = threadIdx.x & 31, y = threadIdx.x >> 5;   // y in 0..7
  int c0 = bx * 32, r0 = by * 32;
#pragma unroll
  for (int i = 0; i < 4; ++i)
    tile[y + i*8][x] = src[(r0 + y + i*8) * Ccols + c0 + x];
  __syncthreads();
#pragma unroll
  for (int i = 0; i < 4; ++i)
    dst[(c0 + y + i*8) * R + r0 + x] = f2bf(tile[x][y + i*8]);
}

// ---------------------------------------------------------------------------
// Generic bf16 GEMM tile body: C[M][ldc](f32) = A[M][512](bf16) * Bt[N][512]^T + bias
// BM=BN=128, BK=64, 256 threads = 4 waves (2x2), wave tile 64x64 = 4x4 frags.
// LDS tiles chunk-XOR-swizzled (slot s of row r holds k-chunk s^(r&7)),
// achieved with linear global_load_lds dest + pre-swizzled global source.
// ---------------------------------------------------------------------------
__device__ __forceinline__ void gemm_body(const unsigned short* __restrict__ A,
                                          const unsigned short* __restrict__ Bt,
                                          const float* __restrict__ bias,
                                          float* __restrict__ C,
                                          int Mvalid, int ldc, int mt, int nt)
{
  __shared__ unsigned short lza[128*64];
  __shared__ unsigned short lzb[128*64];
  const int tid  = threadIdx.x;
  const int wave = tid >> 6;
  const int lane = tid & 63;
  const int row0 = mt * 128;
  const int col0 = nt * 128;
  const int wm = (wave >> 1) * 64;
  const int wn = (wave & 1) * 64;

  // staging: wave w stages rows [w*32, w*32+32) of both tiles, 8 rows/instr.
  const int rloc0 = wave*32 + (lane >> 3);
  const int srcc  = (lane & 7) ^ (rloc0 & 7);   // pre-swizzled source chunk
  const unsigned short* gA = A  + (row0 + rloc0)*DM + srcc*8;
  const unsigned short* gB = Bt + (col0 + rloc0)*DM + srcc*8;
  unsigned short* ldsA = &lza[(wave*32)*64];
  unsigned short* ldsB = &lzb[(wave*32)*64];

  f32x4 acc[4][4] = {};

  for (int kt = 0; kt < DM/64; ++kt) {
    __syncthreads();                       // prior compute done before overwrite
#pragma unroll
    for (int i = 0; i < 4; ++i) {
      gload_lds16(gA + i*8*DM, ldsA + i*8*64);
      gload_lds16(gB + i*8*DM, ldsB + i*8*64);
    }
    gA += 64; gB += 64;
    __syncthreads();                       // barrier drains vmcnt -> tiles ready
#pragma unroll
    for (int kk = 0; kk < 2; ++kk) {
      s16x8 af[4], bfr[4];
#pragma unroll
      for (int m = 0; m < 4; ++m) {
        int r = wm + m*16 + (lane & 15);
        int c = (kk*4 + (lane >> 4)) ^ (r & 7);
        af[m] = *(const s16x8*)&lza[r*64 + c*8];
      }
#pragma unroll
      for (int n = 0; n < 4; ++n) {
        int r = wn + n*16 + (lane & 15);
        int c = (kk*4 + (lane >> 4)) ^ (r & 7);
        bfr[n] = *(const s16x8*)&lzb[r*64 + c*8];
      }
#pragma unroll
      for (int m = 0; m < 4; ++m)
#pragma unroll
        for (int n = 0; n < 4; ++n)
          acc[m][n] = __builtin_amdgcn_mfma_f32_16x16x32_bf16(af[m], bfr[n], acc[m][n], 0, 0, 0);
    }
  }

  // epilogue: C/D layout col = lane&15, row = (lane>>4)*4 + j  (m89/m91 verified)
  const int cl = lane & 15, rq = (lane >> 4) * 4;
#pragma unroll
  for (int n = 0; n < 4; ++n) {
    int col = col0 + wn + n*16 + cl;
    float bv = bias[col];
#pragma unroll
    for (int m = 0; m < 4; ++m) {
      int rb = row0 + wm + m*16 + rq;
#pragma unroll
      for (int j = 0; j < 4; ++j) {
        int r = rb + j;
        if (r < Mvalid) C[(long)r * ldc + col] = acc[m][n][j] + bv;
      }
    }
  }
}

// f and g GEMMs fused in one launch: grid (10, 4, 2); z=1 (pred) uses 4 m-tiles.
__global__ __launch_bounds__(256, 2) void k_gemm_fg(
    const unsigned short* __restrict__ encb,  const unsigned short* __restrict__ WeT,
    const float* __restrict__ b_enc,  float* __restrict__ f,
    const unsigned short* __restrict__ predb, const unsigned short* __restrict__ WpT,
    const float* __restrict__ b_pred, float* __restrict__ g)
{
  const unsigned short* A;  const unsigned short* Bt;
  const float* bias; float* C; int Mv;
  if (blockIdx.z == 0) { A = encb;  Bt = WeT; bias = b_enc;  C = f; Mv = M_ENC_PAD; }
  else {
    if (blockIdx.x >= M_PRED_PAD/128) return;
    A = predb; Bt = WpT; bias = b_pred; C = g; Mv = M_PRED_PAD;
  }
  gemm_body(A, Bt, bias, C, Mv, DM, blockIdx.x, blockIdx.y);
}

// ---------------------------------------------------------------------------
// A-build: Abuf[r][k] = bf16(tanh(f[bt(r)][k] + g[bu(r)][k])), pad rows zero.
// One 16B chunk per thread; grid 30016 x 256.
// ---------------------------------------------------------------------------
__global__ void k_build_a(const float* __restrict__ f, const float* __restrict__ g,
                          unsigned short* __restrict__ Abuf)
{
  int idx = blockIdx.x * 256 + threadIdx.x;   // chunk id < 120064*64
  int r = idx >> 6;
  int k = (idx & 63) * 8;
  s16x8 v;
  if (r < M_MAIN) {
    int b   = r / (T_*U_);
    int rem = r - b * (T_*U_);
    int t   = rem / U_;
    int u   = rem - t * U_;
    const float* fr = f + (b*T_ + t) * DM + k;
    const float* gr = g + (b*U_ + u) * DM + k;
    f32x4 f0 = *(const f32x4*)fr;
    f32x4 f1 = *(const f32x4*)(fr + 4);
    f32x4 g0 = *(const f32x4*)gr;
    f32x4 g1 = *(const f32x4*)(gr + 4);
#pragma unroll
    for (int j = 0; j < 4; ++j) {
      v[j]   = (short)f2bf(fast_tanh(f0[j] + g0[j]));
      v[4+j] = (short)f2bf(fast_tanh(f1[j] + g1[j]));
    }
  } else {
#pragma unroll
    for (int j = 0; j < 8; ++j) v[j] = 0;
  }
  *(s16x8*)(Abuf + (long)idx * 8) = v;
}

// Main GEMM: [120000 x 1024] = A[120064 x 512] * WjT[1024 x 512]^T + b_joint
__global__ __launch_bounds__(256, 2) void k_gemm_main(
    const unsigned short* __restrict__ A, const unsigned short* __restrict__ Bt,
    const float* __restrict__ bias, float* __restrict__ C)
{
  gemm_body(A, Bt, bias, C, M_MAIN, VOC, blockIdx.x, blockIdx.y);
}

// ---------------------------------------------------------------------------
extern "C" void kernel_launch(void* const* d_in, const int* in_sizes, int n_in,
                              void* d_out, int out_size, void* d_ws, size_t ws_size,
                              hipStream_t stream)
{
  const float* enc    = (const float*)d_in[0];
  const float* pred   = (const float*)d_in[1];
  const float* W_enc  = (const float*)d_in[2];
  const float* b_enc  = (const float*)d_in[3];
  const float* W_pred = (const float*)d_in[4];
  const float* b_pred = (const float*)d_in[5];
  const float* W_joint= (const float*)d_in[6];
  const float* b_joint= (const float*)d_in[7];
  float* out = (float*)d_out;

  // workspace carve-up (~124.5 MiB total)
  char* w = (char*)d_ws;
  unsigned short* encb  = (unsigned short*)w; w += (long)M_ENC_PAD*DM*2;
  unsigned short* predb = (unsigned short*)w; w += (long)M_PRED_PAD*DM*2;
  unsigned short* WeT   = (unsigned short*)w; w += (long)DM*DM*2;
  unsigned short* WpT   = (unsigned short*)w; w += (long)DM*DM*2;
  unsigned short* WjT   = (unsigned short*)w; w += (long)VOC*DM*2;
  float*          f     = (float*)w;          w += (long)M_ENC_PAD*DM*4;
  float*          g     = (float*)w;          w += (long)M_PRED_PAD*DM*4;
  unsigned short* Abuf  = (unsigned short*)w; w += (long)M_MAIN_PAD*DM*2;

  k_cvtpad    <<<dim3(448),        dim3(256), 0, stream>>>(enc, pred, encb, predb);
  k_transpose3<<<dim3(32, 16, 3),  dim3(256), 0, stream>>>(W_enc, W_pred, W_joint, WeT, WpT, WjT);
  k_gemm_fg   <<<dim3(10, 4, 2),   dim3(256), 0, stream>>>(encb, WeT, b_enc, f, predb, WpT, b_pred, g);
  k_build_a   <<<dim3((M_MAIN_PAD*64)/256), dim3(256), 0, stream>>>(f, g, Abuf);
  k_gemm_main <<<dim3(938, 8),     dim3(256), 0, stream>>>(Abuf, WjT, b_joint, out);
}

// Round 2
// 292.586 us; speedup vs baseline: 1.1987x; 1.1987x over previous
//
#include <hip/hip_runtime.h>
#include <hip/hip_bf16.h>
#include <cstdint>

// ---------------------------------------------------------------------------
// TransducerJoint: out[b,t,u,:] = tanh(f[b,t,:] + g[b,u,:]) @ W_joint + b_joint
//   f = enc @ W_enc + b_enc   [B*T, 512]
//   g = pred @ W_pred + b_pred [B*U, 512]
// bf16 MFMA GEMMs; A = tanh(f+g) materialized as bf16 in ws (123 MB).
// R1 -> R2 changes (theory: memory-bound, 4x A re-fetch):
//   * n-fastest block order in main GEMM (A-panel L3/L2 reuse)
//   * __launch_bounds__(256,4) on main GEMM (132 -> <=128 unified regs)
//   * nontemporal C stores (stream-once output, keep A resident)
// ---------------------------------------------------------------------------

typedef __attribute__((ext_vector_type(4))) float f32x4;
typedef __attribute__((ext_vector_type(8))) short s16x8;

#define B_ 4
#define T_ 300
#define U_ 100
#define DM 512
#define VOC 1024
#define M_MAIN (B_*T_*U_)       // 120000
#define M_MAIN_PAD 120064       // 938 * 128
#define M_ENC_PAD 1280          // 10 * 128 (valid 1200)
#define M_PRED_PAD 512          // 4 * 128 (valid 400)

__device__ __forceinline__ unsigned short f2bf(float x) {
  unsigned int u = __builtin_bit_cast(unsigned int, x);
  u += 0x7FFFu + ((u >> 16) & 1u);          // round-to-nearest-even
  return (unsigned short)(u >> 16);
}

__device__ __forceinline__ float fast_tanh(float x) {
  // tanh(x) = 1 - 2/(e^{2x}+1);  e^{2x} = 2^{2x*log2(e)}
  float e = __builtin_amdgcn_exp2f(x * 2.8853900817779268f);
  return fmaf(-2.0f, __builtin_amdgcn_rcpf(e + 1.0f), 1.0f);
}

__device__ __forceinline__ void gload_lds16(const void* g, void* l) {
  __builtin_amdgcn_global_load_lds(
      (const __attribute__((address_space(1))) void*)g,
      (__attribute__((address_space(3))) void*)l, 16, 0, 0);
}

// ---------------------------------------------------------------------------
// bf16 convert + row-pad (zeros) for enc and pred, one launch.
// ---------------------------------------------------------------------------
__global__ void k_cvtpad(const float* __restrict__ enc, const float* __restrict__ pred,
                         unsigned short* __restrict__ encb, unsigned short* __restrict__ predb)
{
  int idx = blockIdx.x * 256 + threadIdx.x;
  const int encCh = M_ENC_PAD * 64;   // 81920 16B-chunks
  const float* src; unsigned short* dst; int Mv; int id2;
  if (idx < encCh) { src = enc; dst = encb; Mv = B_*T_; id2 = idx; }
  else            { id2 = idx - encCh; src = pred; dst = predb; Mv = B_*U_; }
  int r = id2 >> 6, k = (id2 & 63) * 8;
  s16x8 v;
  if (r < Mv) {
    f32x4 a = *(const f32x4*)(src + r*DM + k);
    f32x4 b = *(const f32x4*)(src + r*DM + k + 4);
#pragma unroll
    for (int j = 0; j < 4; ++j) { v[j] = (short)f2bf(a[j]); v[4+j] = (short)f2bf(b[j]); }
  } else {
#pragma unroll
    for (int j = 0; j < 8; ++j) v[j] = 0;
  }
  *(s16x8*)(dst + (long)id2 * 8) = v;
}

// ---------------------------------------------------------------------------
// Transpose fp32 [R][C] -> bf16 [C][R] via 32x32 LDS tile. z selects matrix.
// ---------------------------------------------------------------------------
__global__ void k_transpose3(const float* __restrict__ We, const float* __restrict__ Wp,
                             const float* __restrict__ Wj,
                             unsigned short* __restrict__ WeT, unsigned short* __restrict__ WpT,
                             unsigned short* __restrict__ WjT)
{
  __shared__ float tile[32][33];
  const float* src; unsigned short* dst; int Ccols;
  const int R = 512;
  if (blockIdx.z == 0)      { src = We; dst = WeT; Ccols = 512; }
  else if (blockIdx.z == 1) { src = Wp; dst = WpT; Ccols = 512; }
  else                      { src = Wj; dst = WjT; Ccols = 1024; }
  int bx = blockIdx.x, by = blockIdx.y;
  if (bx * 32 >= Ccols) return;
  int x = threadIdx.x & 31, y = threadIdx.x >> 5;   // y in 0..7
  int c0 = bx * 32, r0 = by * 32;
#pragma unroll
  for (int i = 0; i < 4; ++i)
    tile[y + i*8][x] = src[(r0 + y + i*8) * Ccols + c0 + x];
  __syncthreads();
#pragma unroll
  for (int i = 0; i < 4; ++i)
    dst[(c0 + y + i*8) * R + r0 + x] = f2bf(tile[x][y + i*8]);
}

// ---------------------------------------------------------------------------
// Generic bf16 GEMM tile body: C[M][ldc](f32) = A[M][512](bf16) * Bt[N][512]^T + bias
// BM=BN=128, BK=64, 256 threads = 4 waves (2x2), wave tile 64x64 = 4x4 frags.
// LDS tiles chunk-XOR-swizzled (slot s of row r holds k-chunk s^(r&7)),
// achieved with linear global_load_lds dest + pre-swizzled global source.
// ---------------------------------------------------------------------------
__device__ __forceinline__ void gemm_body(const unsigned short* __restrict__ A,
                                          const unsigned short* __restrict__ Bt,
                                          const float* __restrict__ bias,
                                          float* __restrict__ C,
                                          int Mvalid, int ldc, int mt, int nt)
{
  __shared__ unsigned short lza[128*64];
  __shared__ unsigned short lzb[128*64];
  const int tid  = threadIdx.x;
  const int wave = tid >> 6;
  const int lane = tid & 63;
  const int row0 = mt * 128;
  const int col0 = nt * 128;
  const int wm = (wave >> 1) * 64;
  const int wn = (wave & 1) * 64;

  // staging: wave w stages rows [w*32, w*32+32) of both tiles, 8 rows/instr.
  const int rloc0 = wave*32 + (lane >> 3);
  const int srcc  = (lane & 7) ^ (rloc0 & 7);   // pre-swizzled source chunk
  const unsigned short* gA = A  + (row0 + rloc0)*DM + srcc*8;
  const unsigned short* gB = Bt + (col0 + rloc0)*DM + srcc*8;
  unsigned short* ldsA = &lza[(wave*32)*64];
  unsigned short* ldsB = &lzb[(wave*32)*64];

  f32x4 acc[4][4] = {};

  for (int kt = 0; kt < DM/64; ++kt) {
    __syncthreads();                       // prior compute done before overwrite
#pragma unroll
    for (int i = 0; i < 4; ++i) {
      gload_lds16(gA + i*8*DM, ldsA + i*8*64);
      gload_lds16(gB + i*8*DM, ldsB + i*8*64);
    }
    gA += 64; gB += 64;
    __syncthreads();                       // barrier drains vmcnt -> tiles ready
#pragma unroll
    for (int kk = 0; kk < 2; ++kk) {
      s16x8 af[4], bfr[4];
#pragma unroll
      for (int m = 0; m < 4; ++m) {
        int r = wm + m*16 + (lane & 15);
        int c = (kk*4 + (lane >> 4)) ^ (r & 7);
        af[m] = *(const s16x8*)&lza[r*64 + c*8];
      }
#pragma unroll
      for (int n = 0; n < 4; ++n) {
        int r = wn + n*16 + (lane & 15);
        int c = (kk*4 + (lane >> 4)) ^ (r & 7);
        bfr[n] = *(const s16x8*)&lzb[r*64 + c*8];
      }
#pragma unroll
      for (int m = 0; m < 4; ++m)
#pragma unroll
        for (int n = 0; n < 4; ++n)
          acc[m][n] = __builtin_amdgcn_mfma_f32_16x16x32_bf16(af[m], bfr[n], acc[m][n], 0, 0, 0);
    }
  }

  // epilogue: C/D layout col = lane&15, row = (lane>>4)*4 + j  (m89/m91 verified)
  // nontemporal: output is stream-once; don't evict A from L2/L3.
  const int cl = lane & 15, rq = (lane >> 4) * 4;
#pragma unroll
  for (int n = 0; n < 4; ++n) {
    int col = col0 + wn + n*16 + cl;
    float bv = bias[col];
#pragma unroll
    for (int m = 0; m < 4; ++m) {
      int rb = row0 + wm + m*16 + rq;
#pragma unroll
      for (int j = 0; j < 4; ++j) {
        int r = rb + j;
        if (r < Mvalid) __builtin_nontemporal_store(acc[m][n][j] + bv, &C[(long)r * ldc + col]);
      }
    }
  }
}

// f and g GEMMs fused in one launch: grid (10, 4, 2); z=1 (pred) uses 4 m-tiles.
__global__ __launch_bounds__(256, 2) void k_gemm_fg(
    const unsigned short* __restrict__ encb,  const unsigned short* __restrict__ WeT,
    const float* __restrict__ b_enc,  float* __restrict__ f,
    const unsigned short* __restrict__ predb, const unsigned short* __restrict__ WpT,
    const float* __restrict__ b_pred, float* __restrict__ g)
{
  const unsigned short* A;  const unsigned short* Bt;
  const float* bias; float* C; int Mv;
  if (blockIdx.z == 0) { A = encb;  Bt = WeT; bias = b_enc;  C = f; Mv = M_ENC_PAD; }
  else {
    if (blockIdx.x >= M_PRED_PAD/128) return;
    A = predb; Bt = WpT; bias = b_pred; C = g; Mv = M_PRED_PAD;
  }
  gemm_body(A, Bt, bias, C, Mv, DM, blockIdx.x, blockIdx.y);
}

// ---------------------------------------------------------------------------
// A-build: Abuf[r][k] = bf16(tanh(f[bt(r)][k] + g[bu(r)][k])), pad rows zero.
// ---------------------------------------------------------------------------
__global__ void k_build_a(const float* __restrict__ f, const float* __restrict__ g,
                          unsigned short* __restrict__ Abuf)
{
  int idx = blockIdx.x * 256 + threadIdx.x;   // chunk id < 120064*64
  int r = idx >> 6;
  int k = (idx & 63) * 8;
  s16x8 v;
  if (r < M_MAIN) {
    int b   = r / (T_*U_);
    int rem = r - b * (T_*U_);
    int t   = rem / U_;
    int u   = rem - t * U_;
    const float* fr = f + (b*T_ + t) * DM + k;
    const float* gr = g + (b*U_ + u) * DM + k;
    f32x4 f0 = *(const f32x4*)fr;
    f32x4 f1 = *(const f32x4*)(fr + 4);
    f32x4 g0 = *(const f32x4*)gr;
    f32x4 g1 = *(const f32x4*)(gr + 4);
#pragma unroll
    for (int j = 0; j < 4; ++j) {
      v[j]   = (short)f2bf(fast_tanh(f0[j] + g0[j]));
      v[4+j] = (short)f2bf(fast_tanh(f1[j] + g1[j]));
    }
  } else {
#pragma unroll
    for (int j = 0; j < 8; ++j) v[j] = 0;
  }
  *(s16x8*)(Abuf + (long)idx * 8) = v;
}

// Main GEMM: [120000 x 1024] = A[120064 x 512] * WjT[1024 x 512]^T + b_joint
// n-fastest ordering: all 8 n-tiles of an A-panel dispatch adjacently, so the
// 128 KB panel is L2/L3-resident for 7 of its 8 reads (fixes 4x HBM re-fetch).
__global__ __launch_bounds__(256, 4) void k_gemm_main(
    const unsigned short* __restrict__ A, const unsigned short* __restrict__ Bt,
    const float* __restrict__ bias, float* __restrict__ C)
{
  int bid = blockIdx.x;
  int mt = bid >> 3;        // 938 panels
  int nt = bid & 7;         // 8 n-tiles, adjacent in dispatch order
  gemm_body(A, Bt, bias, C, M_MAIN, VOC, mt, nt);
}

// ---------------------------------------------------------------------------
extern "C" void kernel_launch(void* const* d_in, const int* in_sizes, int n_in,
                              void* d_out, int out_size, void* d_ws, size_t ws_size,
                              hipStream_t stream)
{
  const float* enc    = (const float*)d_in[0];
  const float* pred   = (const float*)d_in[1];
  const float* W_enc  = (const float*)d_in[2];
  const float* b_enc  = (const float*)d_in[3];
  const float* W_pred = (const float*)d_in[4];
  const float* b_pred = (const float*)d_in[5];
  const float* W_joint= (const float*)d_in[6];
  const float* b_joint= (const float*)d_in[7];
  float* out = (float*)d_out;

  // workspace carve-up (~124.5 MiB total)
  char* w = (char*)d_ws;
  unsigned short* encb  = (unsigned short*)w; w += (long)M_ENC_PAD*DM*2;
  unsigned short* predb = (unsigned short*)w; w += (long)M_PRED_PAD*DM*2;
  unsigned short* WeT   = (unsigned short*)w; w += (long)DM*DM*2;
  unsigned short* WpT   = (unsigned short*)w; w += (long)DM*DM*2;
  unsigned short* WjT   = (unsigned short*)w; w += (long)VOC*DM*2;
  float*          f     = (float*)w;          w += (long)M_ENC_PAD*DM*4;
  float*          g     = (float*)w;          w += (long)M_PRED_PAD*DM*4;
  unsigned short* Abuf  = (unsigned short*)w; w += (long)M_MAIN_PAD*DM*2;

  k_cvtpad    <<<dim3(448),        dim3(256), 0, stream>>>(enc, pred, encb, predb);
  k_transpose3<<<dim3(32, 16, 3),  dim3(256), 0, stream>>>(W_enc, W_pred, W_joint, WeT, WpT, WjT);
  k_gemm_fg   <<<dim3(10, 4, 2),   dim3(256), 0, stream>>>(encb, WeT, b_enc, f, predb, WpT, b_pred, g);
  k_build_a   <<<dim3((M_MAIN_PAD*64)/256), dim3(256), 0, stream>>>(f, g, Abuf);
  k_gemm_main <<<dim3(938*8),      dim3(256), 0, stream>>>(Abuf, WjT, b_joint, out);
}